// Round 2
// baseline (189.766 us; speedup 1.0000x reference)
//
#include <hip/hip_runtime.h>
#include <hip/hip_bf16.h>

#define NROWS 16384   // B*S = 4*4096
#define KD    2048    // D
#define NE    16      // experts
#define KSPLIT 8      // waves per block, each owns KD/KSPLIT = 256
#define ROWS_PER_BLK 64

// One fused kernel:
//   per block: 64 rows, 8 waves split K (256 each), lane <-> row.
//   W addresses are wave-uniform -> scalar loads; x read per-lane-row float4.
//   LDS cross-wave reduce (two 16-out passes), wave 0 does epilogue.
// Output buffer is FLOAT32: [262144 probs][32768 ids-as-floats].
__global__ __launch_bounds__(512, 2)
void noisy_router_kernel(const float* __restrict__ x,
                         const float* __restrict__ noise,
                         const float* __restrict__ Wfc,
                         const float* __restrict__ bfc,
                         const float* __restrict__ Wns,
                         const float* __restrict__ bns,
                         float* __restrict__ out)
{
    __shared__ float slab[KSPLIT][ROWS_PER_BLK][NE + 1];  // 34816 B
    __shared__ float redA[NE][ROWS_PER_BLK + 1];          //  4160 B
    __shared__ float redB[NE][ROWS_PER_BLK + 1];          //  4160 B

    const int tid  = threadIdx.x;
    const int lane = tid & 63;
    const int w    = tid >> 6;                       // k-slice id 0..7
    const int row  = blockIdx.x * ROWS_PER_BLK + lane;
    const int k0   = __builtin_amdgcn_readfirstlane(w * (KD / KSPLIT));

    const float* xp  = x   + (size_t)row * KD + k0;
    const float* wa0 = Wfc + k0;
    const float* wb0 = Wns + k0;

    float accA[NE], accB[NE];
    #pragma unroll
    for (int e = 0; e < NE; ++e) { accA[e] = 0.f; accB[e] = 0.f; }

    float4 cur[4];
    #pragma unroll
    for (int j = 0; j < 4; ++j) cur[j] = ((const float4*)xp)[j];

    // 16 chunks of 16 floats over this wave's K-slice, prefetch next chunk.
    #pragma unroll 1
    for (int c = 0; c < 16; ++c) {
        float4 nxt[4];
        if (c < 15) {
            const float4* xn = (const float4*)(xp + (c + 1) * 16);
            #pragma unroll
            for (int j = 0; j < 4; ++j) nxt[j] = xn[j];
        }
        const float* wa = wa0 + c * 16;
        const float* wb = wb0 + c * 16;
        #pragma unroll
        for (int e = 0; e < NE; ++e) {
            const float4* a4 = (const float4*)(wa + e * KD);
            const float4* b4 = (const float4*)(wb + e * KD);
            #pragma unroll
            for (int j = 0; j < 4; ++j) {
                const float4 a = a4[j], b = b4[j], xv = cur[j];
                accA[e] = fmaf(xv.x, a.x, accA[e]);
                accA[e] = fmaf(xv.y, a.y, accA[e]);
                accA[e] = fmaf(xv.z, a.z, accA[e]);
                accA[e] = fmaf(xv.w, a.w, accA[e]);
                accB[e] = fmaf(xv.x, b.x, accB[e]);
                accB[e] = fmaf(xv.y, b.y, accB[e]);
                accB[e] = fmaf(xv.z, b.z, accB[e]);
                accB[e] = fmaf(xv.w, b.w, accB[e]);
            }
        }
        if (c < 15) {
            #pragma unroll
            for (int j = 0; j < 4; ++j) cur[j] = nxt[j];
        }
    }

    // ---- cross-wave reduction, pass A (fc logits) ----
    #pragma unroll
    for (int j = 0; j < NE; ++j) slab[w][lane][j] = accA[j];
    __syncthreads();
    {
        const int idx = tid * 2;          // 1024 (row,out) pairs / 512 threads
        const int r   = idx >> 4;         // 0..63
        const int o   = idx & 15;         // even
        float s0 = 0.f, s1 = 0.f;
        #pragma unroll
        for (int v = 0; v < KSPLIT; ++v) { s0 += slab[v][r][o]; s1 += slab[v][r][o + 1]; }
        redA[o][r]     = s0 + bfc[o];
        redA[o + 1][r] = s1 + bfc[o + 1];
    }
    __syncthreads();

    // ---- cross-wave reduction, pass B (noisy logits) ----
    #pragma unroll
    for (int j = 0; j < NE; ++j) slab[w][lane][j] = accB[j];
    __syncthreads();
    {
        const int idx = tid * 2;
        const int r   = idx >> 4;
        const int o   = idx & 15;
        float s0 = 0.f, s1 = 0.f;
        #pragma unroll
        for (int v = 0; v < KSPLIT; ++v) { s0 += slab[v][r][o]; s1 += slab[v][r][o + 1]; }
        redB[o][r]     = s0 + bns[o];
        redB[o + 1][r] = s1 + bns[o + 1];
    }
    __syncthreads();

    // ---- epilogue: one row per lane of wave 0 ----
    if (tid < ROWS_PER_BLK) {
        const int r = tid;
        const size_t grow = (size_t)blockIdx.x * ROWS_PER_BLK + r;
        const float* nzp = noise + grow * NE;

        float m1 = -1e30f, m2 = -1e30f;
        int i1 = 0, i2 = 0;
        #pragma unroll
        for (int j = 0; j < NE; ++j) {
            const float z  = redB[j][r];
            // jax.nn.softplus(z) = max(z,0) + log1p(exp(-|z|))
            const float sp = fmaxf(z, 0.f) + log1pf(expf(-fabsf(z)));
            const float v  = fmaf(nzp[j], sp, redA[j][r]);
            // jax.lax.top_k ordering: descending value, ties -> lower index
            if (v > m1)      { m2 = m1; i2 = i1; m1 = v; i1 = j; }
            else if (v > m2) { m2 = v;  i2 = j; }
        }
        const float e2  = expf(m2 - m1);
        const float inv = 1.f / (1.f + e2);
        const float p1  = inv;
        const float p2  = e2 * inv;

        float* po = out + grow * NE;
        #pragma unroll
        for (int j = 0; j < NE; ++j) {
            po[j] = (j == i1) ? p1 : ((j == i2) ? p2 : 0.f);
        }
        float* pi = out + (size_t)NROWS * NE + grow * 2;
        pi[0] = (float)i1;
        pi[1] = (float)i2;
    }
}

extern "C" void kernel_launch(void* const* d_in, const int* in_sizes, int n_in,
                              void* d_out, int out_size, void* d_ws, size_t ws_size,
                              hipStream_t stream)
{
    const float* x     = (const float*)d_in[0];
    const float* noise = (const float*)d_in[1];
    const float* Wfc   = (const float*)d_in[2];
    const float* bfc   = (const float*)d_in[3];
    const float* Wns   = (const float*)d_in[4];
    const float* bns   = (const float*)d_in[5];
    float* out = (float*)d_out;

    noisy_router_kernel<<<NROWS / ROWS_PER_BLK, 512, 0, stream>>>(
        x, noise, Wfc, bfc, Wns, bns, out);
}

// Round 4
// 166.383 us; speedup vs baseline: 1.1405x; 1.1405x over previous
//
#include <hip/hip_runtime.h>
#include <hip/hip_bf16.h>

#define NROWS 16384   // B*S
#define KD    2048    // D
#define NE    16      // experts
#define KSPLIT 8      // waves per block, each owns TK/KSPLIT = 8 floats per tile
#define ROWS_PER_BLK 64
#define TK    64      // K-floats staged per tile
#define NT    (KD / TK)   // 32 tiles

// Fused noisy-router:
//  - x staged to LDS in coalesced, XOR-swizzled, double-buffered 64x64 tiles
//  - lane = row, wave = K-slice; W via wave-uniform (scalar) loads
//  - LDS cross-wave reduce, wave0 epilogue (softplus, top-2, 2-way softmax)
// Output buffer FLOAT32: [262144 probs][32768 ids-as-floats].
__global__ __launch_bounds__(512)
void noisy_router_kernel(const float* __restrict__ x,
                         const float* __restrict__ noise,
                         const float* __restrict__ Wfc,
                         const float* __restrict__ bfc,
                         const float* __restrict__ Wns,
                         const float* __restrict__ bns,
                         float* __restrict__ out)
{
    __shared__ float stage[2][ROWS_PER_BLK * TK];      // 32 KB (also epilogue slab)
    __shared__ float redA[NE][ROWS_PER_BLK + 1];       // 4160 B
    __shared__ float redB[NE][ROWS_PER_BLK + 1];       // 4160 B

    const int tid  = threadIdx.x;
    const int lane = tid & 63;
    const int w    = tid >> 6;                         // K-slice id 0..7
    const int wko  = __builtin_amdgcn_readfirstlane(w * 8);  // uniform K offset in tile

    // ---- staging map: thread loads rows r0 and r0+32, float4 column c4 ----
    const int r0 = tid >> 4;          // 0..31
    const int c4 = tid & 15;          // 0..15
    const int slot = c4 ^ (r0 & 15);  // same for r0+32
    const int dst0 = r0 * TK + slot * 4;
    const int dst1 = dst0 + 32 * TK;
    const float* xg0 = x + (size_t)(blockIdx.x * ROWS_PER_BLK + r0) * KD + c4 * 4;
    const float* xg1 = xg0 + (size_t)32 * KD;

    // ---- compute-side read offsets: lane l = row l, slots (2w)^ and (2w+1)^ ----
    const int rd0 = lane * TK + (((2 * w + 0)) ^ (lane & 15)) * 4;
    const int rd1 = lane * TK + (((2 * w + 1)) ^ (lane & 15)) * 4;

    float accA[NE], accB[NE];
    #pragma unroll
    for (int e = 0; e < NE; ++e) { accA[e] = 0.f; accB[e] = 0.f; }

    // prologue: tile 0 into regs
    float4 a0 = *(const float4*)xg0;
    float4 a1 = *(const float4*)xg1;

    #pragma unroll 1
    for (int t = 0; t < NT; ++t) {
        float* st = stage[t & 1];
        *(float4*)(st + dst0) = a0;
        *(float4*)(st + dst1) = a1;
        __syncthreads();

        if (t + 1 < NT) {                       // issue next tile early
            a0 = *(const float4*)(xg0 + (size_t)(t + 1) * TK);
            a1 = *(const float4*)(xg1 + (size_t)(t + 1) * TK);
        }

        const float4 xv0 = *(const float4*)(st + rd0);
        const float4 xv1 = *(const float4*)(st + rd1);
        const float* wa = Wfc + t * TK + wko;   // wave-uniform -> s_load
        const float* wb = Wns + t * TK + wko;

        #pragma unroll
        for (int e = 0; e < NE; ++e) {
            const float4 A0 = *(const float4*)(wa + e * KD);
            const float4 A1 = *(const float4*)(wa + e * KD + 4);
            const float4 B0 = *(const float4*)(wb + e * KD);
            const float4 B1 = *(const float4*)(wb + e * KD + 4);
            accA[e] = fmaf(xv0.x, A0.x, accA[e]);
            accA[e] = fmaf(xv0.y, A0.y, accA[e]);
            accA[e] = fmaf(xv0.z, A0.z, accA[e]);
            accA[e] = fmaf(xv0.w, A0.w, accA[e]);
            accA[e] = fmaf(xv1.x, A1.x, accA[e]);
            accA[e] = fmaf(xv1.y, A1.y, accA[e]);
            accA[e] = fmaf(xv1.z, A1.z, accA[e]);
            accA[e] = fmaf(xv1.w, A1.w, accA[e]);
            accB[e] = fmaf(xv0.x, B0.x, accB[e]);
            accB[e] = fmaf(xv0.y, B0.y, accB[e]);
            accB[e] = fmaf(xv0.z, B0.z, accB[e]);
            accB[e] = fmaf(xv0.w, B0.w, accB[e]);
            accB[e] = fmaf(xv1.x, B1.x, accB[e]);
            accB[e] = fmaf(xv1.y, B1.y, accB[e]);
            accB[e] = fmaf(xv1.z, B1.z, accB[e]);
            accB[e] = fmaf(xv1.w, B1.w, accB[e]);
        }
        __syncthreads();
    }

    // ---- epilogue: reuse stage[] as slab[KSPLIT][64][16] (8192 floats) ----
    float* slab = &stage[0][0];

    #pragma unroll
    for (int j = 0; j < NE; ++j) slab[w * 1024 + lane * 16 + j] = accA[j];
    __syncthreads();
    {
        const int idx = tid * 2;           // 1024 (row,out) pairs
        const int r   = idx >> 4;
        const int o   = idx & 15;
        float s0 = 0.f, s1 = 0.f;
        #pragma unroll
        for (int v = 0; v < KSPLIT; ++v) {
            s0 += slab[v * 1024 + r * 16 + o];
            s1 += slab[v * 1024 + r * 16 + o + 1];
        }
        redA[o][r]     = s0 + bfc[o];
        redA[o + 1][r] = s1 + bfc[o + 1];
    }
    __syncthreads();

    #pragma unroll
    for (int j = 0; j < NE; ++j) slab[w * 1024 + lane * 16 + j] = accB[j];
    __syncthreads();
    {
        const int idx = tid * 2;
        const int r   = idx >> 4;
        const int o   = idx & 15;
        float s0 = 0.f, s1 = 0.f;
        #pragma unroll
        for (int v = 0; v < KSPLIT; ++v) {
            s0 += slab[v * 1024 + r * 16 + o];
            s1 += slab[v * 1024 + r * 16 + o + 1];
        }
        redB[o][r]     = s0 + bns[o];
        redB[o + 1][r] = s1 + bns[o + 1];
    }
    __syncthreads();

    // ---- final per-row: softplus noise, top-2, sparse softmax ----
    if (tid < ROWS_PER_BLK) {
        const int r = tid;
        const size_t grow = (size_t)blockIdx.x * ROWS_PER_BLK + r;
        const float* nzp = noise + grow * NE;

        float m1 = -1e30f, m2 = -1e30f;
        int i1 = 0, i2 = 0;
        #pragma unroll
        for (int j = 0; j < NE; ++j) {
            const float z  = redB[j][r];
            const float sp = fmaxf(z, 0.f) + log1pf(expf(-fabsf(z)));  // jax softplus
            const float v  = fmaf(nzp[j], sp, redA[j][r]);
            if (v > m1)      { m2 = m1; i2 = i1; m1 = v; i1 = j; }     // ties -> lower idx
            else if (v > m2) { m2 = v;  i2 = j; }
        }
        const float e2  = expf(m2 - m1);
        const float inv = 1.f / (1.f + e2);

        float* po = out + grow * NE;
        #pragma unroll
        for (int j = 0; j < NE; ++j) {
            po[j] = (j == i1) ? inv : ((j == i2) ? e2 * inv : 0.f);
        }
        float* pi = out + (size_t)NROWS * NE + grow * 2;
        pi[0] = (float)i1;
        pi[1] = (float)i2;
    }
}

extern "C" void kernel_launch(void* const* d_in, const int* in_sizes, int n_in,
                              void* d_out, int out_size, void* d_ws, size_t ws_size,
                              hipStream_t stream)
{
    const float* x     = (const float*)d_in[0];
    const float* noise = (const float*)d_in[1];
    const float* Wfc   = (const float*)d_in[2];
    const float* bfc   = (const float*)d_in[3];
    const float* Wns   = (const float*)d_in[4];
    const float* bns   = (const float*)d_in[5];
    float* out = (float*)d_out;

    noisy_router_kernel<<<NROWS / ROWS_PER_BLK, 512, 0, stream>>>(
        x, noise, Wfc, bfc, Wns, bns, out);
}